// Round 4
// baseline (1543.648 us; speedup 1.0000x reference)
//
#include <hip/hip_runtime.h>
#include <hip/hip_bf16.h>

typedef unsigned int u32;
typedef unsigned short u16;

#define B_ 64
#define N_ 8192
#define DI 8
#define O_ 10
#define DO_ 16
#define OD 160          // O_*DO_
#define NCHUNK 32       // n per block; grid = N_/NCHUNK = 256 blocks
#define NPART 256       // number of partial buffers (= grid size)
#define SROW 161        // padded fp32 row stride for s_lds (odd -> 2 lanes/bank, free)
#define VROW 162        // padded u16 row stride for v_lds (dword stride 81, odd)

static __device__ __forceinline__ float blo(u32 p) {
    return __uint_as_float(p << 16);
}
static __device__ __forceinline__ float bhi(u32 p) {
    return __uint_as_float(p & 0xFFFF0000u);
}

// PHASE 0: c = 0.1 uniform (softmax of zeros), accumulate 0.1*u_hat into s.
// PHASE 1: t[o] = sum_d u_hat*v, softmax over o, accumulate c[o]*u_hat into s.
//          (routing rounds 1 and 2; v = v0, then v0+v1 since
//           b2 = b1 + u.v1 = u.(v0+v1) -- no b_ij storage needed)
// ATOMIC_TAIL=0: stream block partial to Sout + blockIdx*10240 (no atomics).
// ATOMIC_TAIL=1: atomicAdd into global S (fallback if ws too small).
template <int PHASE, int ATOMIC_TAIL>
__global__ __launch_bounds__(1024, 4)
void caps_pass(const float* __restrict__ Xf, const float* __restrict__ Wf,
               const u16* __restrict__ Vb, float* __restrict__ Sout) {
    __shared__ float s_lds[B_ * SROW];
    __shared__ u16 v_lds[B_ * VROW];

    const int tid = threadIdx.x;
    for (int i = tid; i < B_ * SROW; i += 1024) s_lds[i] = 0.0f;
    if (PHASE > 0) {
        for (int i = tid; i < B_ * OD; i += 1024) {
            int b = i / OD, od = i - b * OD;
            v_lds[b * VROW + od] = Vb[i];
        }
    }
    __syncthreads();

    const int b = tid & 63;                                   // lane = batch index
    const int w = __builtin_amdgcn_readfirstlane(tid >> 6);   // wave id 0..15 (uniform)

    #pragma unroll 1
    for (int k = 0; k < NCHUNK / 16; ++k) {
        const int n = blockIdx.x * NCHUNK + w + 16 * k;       // wave-uniform n

        // x[b][n][0..7]: 8 fp32 = 32 B per lane (two float4 loads)
        const float4 x0 = *(const float4*)(Xf + ((size_t)b * N_ + n) * DI);
        const float4 x1 = *(const float4*)(Xf + ((size_t)b * N_ + n) * DI + 4);
        float xf[8];
        xf[0] = x0.x; xf[1] = x0.y; xf[2] = x0.z; xf[3] = x0.w;
        xf[4] = x1.x; xf[5] = x1.y; xf[6] = x1.z; xf[7] = x1.w;

        // W[n][o][d][i] row base: wave-uniform -> scalar loads (SGPR operand FMAs)
        const float* wrow = Wf + (size_t)n * (O_ * DO_ * DI);

        if (PHASE == 0) {
            #pragma unroll
            for (int o = 0; o < O_; ++o) {
                #pragma unroll
                for (int d = 0; d < DO_; ++d) {
                    const float* wp = wrow + (o * DO_ + d) * DI;
                    float u = 0.0f;
                    #pragma unroll
                    for (int ii = 0; ii < DI; ++ii) u = fmaf(wp[ii], xf[ii], u);
                    atomicAdd(&s_lds[b * SROW + o * DO_ + d], 0.1f * u);
                }
            }
        } else {
            // ---- loop 1: agreement logits t[o] = sum_d u_hat[o,d]*v[b,o,d]
            float t[O_];
            #pragma unroll
            for (int o = 0; o < O_; ++o) {
                float acc = 0.0f;
                #pragma unroll
                for (int d2 = 0; d2 < 8; ++d2) {
                    const int d0 = 2 * d2;
                    const float* wp = wrow + (o * DO_ + d0) * DI;
                    float u0 = 0.0f, u1 = 0.0f;
                    #pragma unroll
                    for (int ii = 0; ii < DI; ++ii) {
                        u0 = fmaf(wp[ii], xf[ii], u0);
                        u1 = fmaf(wp[DI + ii], xf[ii], u1);
                    }
                    const u32 vv = *(const u32*)&v_lds[b * VROW + o * DO_ + d0];
                    acc = fmaf(u0, blo(vv), acc);
                    acc = fmaf(u1, bhi(vv), acc);
                }
                t[o] = acc;
            }
            // ---- softmax over the 10 out-capsules (|t| small, no max-sub needed)
            float e[O_], den = 0.0f;
            #pragma unroll
            for (int o = 0; o < O_; ++o) { e[o] = __expf(t[o]); den += e[o]; }
            const float rinv = 1.0f / den;
            // ---- loop 2: recompute u_hat, accumulate c[o]*u_hat into LDS s
            #pragma unroll
            for (int o = 0; o < O_; ++o) {
                const float c = e[o] * rinv;
                #pragma unroll
                for (int d = 0; d < DO_; ++d) {
                    const float* wp = wrow + (o * DO_ + d) * DI;
                    float u = 0.0f;
                    #pragma unroll
                    for (int ii = 0; ii < DI; ++ii) u = fmaf(wp[ii], xf[ii], u);
                    atomicAdd(&s_lds[b * SROW + o * DO_ + d], c * u);
                }
            }
        }
    }
    __syncthreads();
    if (ATOMIC_TAIL) {
        // fallback: global accumulator (256-way contention -- slow path)
        for (int i = tid; i < B_ * OD; i += 1024) {
            int bb = i / OD, od = i - bb * OD;
            atomicAdd(&Sout[i], s_lds[bb * SROW + od]);
        }
    } else {
        // stream block partial to private slice: coalesced plain stores
        float* myout = Sout + (size_t)blockIdx.x * (B_ * OD);
        for (int i = tid; i < B_ * OD; i += 1024) {
            int bb = i / OD, od = i - bb * OD;
            myout[i] = s_lds[bb * SROW + od];
        }
    }
}

// Fused reduce + squash. One block per b (grid=64, 192 threads, 160 active).
// Sums NPART partials, squashes over the OUT-CAPSULE axis per (b,d), emits v.
// PHASE 0: V0f=v0 (fp32), Vb=bf16(v0).
// PHASE 1: Vb=bf16(v0+v1).
// PHASE 2: out=fp32 v2.
template <int PHASE>
__global__ __launch_bounds__(192)
void caps_reduce_fin(const float* __restrict__ Sp, float* __restrict__ V0f,
                     u16* __restrict__ Vb, float* __restrict__ out) {
    __shared__ float s_s[OD];
    __shared__ float s_scale[DO_];
    const int b = blockIdx.x;
    const int t = threadIdx.x;
    if (t < OD) {
        float acc = 0.0f;
        const float* p0 = Sp + b * OD + t;
        #pragma unroll 8
        for (int p = 0; p < NPART; ++p) acc += p0[(size_t)p * (B_ * OD)];
        s_s[t] = acc;
    }
    __syncthreads();
    if (t < DO_) {
        float norm = 0.0f;
        #pragma unroll
        for (int o = 0; o < O_; ++o) { float x = s_s[o * DO_ + t]; norm = fmaf(x, x, norm); }
        s_scale[t] = norm / (1.0f + norm) * rsqrtf(norm + 1e-9f);
    }
    __syncthreads();
    if (t < OD) {
        const float v = s_s[t] * s_scale[t & 15];
        const int idx = b * OD + t;
        if (PHASE == 0) {
            V0f[idx] = v;
            __hip_bfloat16 h = __float2bfloat16(v);
            Vb[idx] = *(const u16*)&h;
        } else if (PHASE == 1) {
            const float vs = V0f[idx] + v;
            __hip_bfloat16 h = __float2bfloat16(vs);
            Vb[idx] = *(const u16*)&h;
        } else {
            out[idx] = v;
        }
    }
}

// Fallback finalize for the atomic path (also zeroes S for the next pass).
template <int PHASE>
__global__ __launch_bounds__(1024)
void caps_finalize(float* __restrict__ S, float* __restrict__ V0f,
                   u16* __restrict__ Vb, float* __restrict__ out) {
    const int tid = threadIdx.x;      // 1024 = 64 b * 16 d
    const int b = tid >> 4, d = tid & 15;
    float sv[O_];
    float norm = 0.0f;
    #pragma unroll
    for (int o = 0; o < O_; ++o) {
        sv[o] = S[b * OD + o * DO_ + d];
        norm = fmaf(sv[o], sv[o], norm);
    }
    const float scale = norm / (1.0f + norm) * rsqrtf(norm + 1e-9f);
    #pragma unroll
    for (int o = 0; o < O_; ++o) {
        const int idx = b * OD + o * DO_ + d;
        const float v = scale * sv[o];
        if (PHASE == 0) {
            V0f[idx] = v;
            __hip_bfloat16 h = __float2bfloat16(v);
            Vb[idx] = *(const u16*)&h;
            S[idx] = 0.0f;
        } else if (PHASE == 1) {
            const float vs = V0f[idx] + v;
            __hip_bfloat16 h = __float2bfloat16(vs);
            Vb[idx] = *(const u16*)&h;
            S[idx] = 0.0f;
        } else {
            out[idx] = v;
        }
    }
}

extern "C" void kernel_launch(void* const* d_in, const int* in_sizes, int n_in,
                              void* d_out, int out_size, void* d_ws, size_t ws_size,
                              hipStream_t stream) {
    const float* Xf = (const float*)d_in[0];   // x: [64, 8192, 8] fp32
    const float* Wf = (const float*)d_in[1];   // W: [1, 8192, 10, 16, 8] fp32
    float* out = (float*)d_out;

    const size_t part_elems = (size_t)NPART * B_ * OD;
    const size_t need = part_elems * 4 + B_ * OD * 4 + B_ * OD * 2;

    const dim3 grid(N_ / NCHUNK), blk(1024);

    if (ws_size >= need) {
        // ---- fast path: per-block partials + fused reduce/finalize ----
        float* Sp = (float*)d_ws;                  // [NPART][10240] partials
        float* V0f = Sp + part_elems;              // 10240 fp32 (v0)
        u16* Vb = (u16*)(V0f + B_ * OD);           // 10240 bf16 (v for next pass)
        const dim3 rgrid(B_), rblk(192);

        caps_pass<0, 0><<<grid, blk, 0, stream>>>(Xf, Wf, nullptr, Sp);
        caps_reduce_fin<0><<<rgrid, rblk, 0, stream>>>(Sp, V0f, Vb, nullptr);

        caps_pass<1, 0><<<grid, blk, 0, stream>>>(Xf, Wf, Vb, Sp);
        caps_reduce_fin<1><<<rgrid, rblk, 0, stream>>>(Sp, V0f, Vb, nullptr);

        caps_pass<1, 0><<<grid, blk, 0, stream>>>(Xf, Wf, Vb, Sp);
        caps_reduce_fin<2><<<rgrid, rblk, 0, stream>>>(Sp, nullptr, nullptr, out);
    } else {
        // ---- fallback: global atomic accumulator (proven-correct R3 path) ----
        float* S = (float*)d_ws;                   // 10240 fp32 accumulator
        float* V0f = S + B_ * OD;                  // 10240 fp32 (v0)
        u16* Vb = (u16*)(V0f + B_ * OD);           // 10240 bf16
        const dim3 one(1), fblk(1024);

        hipMemsetAsync(S, 0, B_ * OD * sizeof(float), stream);

        caps_pass<0, 1><<<grid, blk, 0, stream>>>(Xf, Wf, nullptr, S);
        caps_finalize<0><<<one, fblk, 0, stream>>>(S, V0f, Vb, nullptr);

        caps_pass<1, 1><<<grid, blk, 0, stream>>>(Xf, Wf, Vb, S);
        caps_finalize<1><<<one, fblk, 0, stream>>>(S, V0f, Vb, nullptr);

        caps_pass<1, 1><<<grid, blk, 0, stream>>>(Xf, Wf, Vb, S);
        caps_finalize<2><<<one, fblk, 0, stream>>>(S, nullptr, nullptr, out);
    }
}